// Round 8
// baseline (11429.450 us; speedup 1.0000x reference)
//
#include <hip/hip_runtime.h>
#include <math.h>

#define NMC    32768
#define TSTEPS 1024
#define PPW    16              // paths per wave
#define WPB    4               // waves per block (independent; no loop barriers)
#define PPB    (PPW*WPB)       // 64 paths per block
#define NBLK   (NMC / PPB)     // 512 blocks
#define TWO_PI 6.28318530717958647692f

typedef short bf16x8 __attribute__((ext_vector_type(8)));
typedef float f32x4  __attribute__((ext_vector_type(4)));

#define MFMA_B16(A, B, C) (C) = __builtin_amdgcn_mfma_f32_16x16x32_bf16((A), (B), (C), 0, 0, 0)

__device__ __forceinline__ float fsilu(float x) { return __fdividef(x, 1.0f + __expf(-x)); }
__device__ __forceinline__ unsigned fbits(float x){ union{float f;unsigned u;}c; c.f=x; return c.u; }
__device__ __forceinline__ float bitsf(unsigned u){ union{float f;unsigned u;}c; c.u=u; return c.f; }
__device__ __forceinline__ bf16x8 mk8(unsigned a,unsigned b,unsigned c,unsigned d){
  union{unsigned u[4]; bf16x8 s;} z; z.u[0]=a; z.u[1]=b; z.u[2]=c; z.u[3]=d; return z.s;
}

// Truncation split: e = H + M + L + O(2^-27 * |e|)  (verified round-6, absmax 0.0)
__device__ __forceinline__ void split3(const float e[8], bf16x8 &H, bf16x8 &M, bf16x8 &L) {
  unsigned dH[4], dM[4], dL[4];
  #pragma unroll
  for (int v = 0; v < 4; ++v) {
    const float a0 = e[2*v], a1 = e[2*v+1];
    const unsigned uH0 = fbits(a0) & 0xFFFF0000u, uH1 = fbits(a1) & 0xFFFF0000u;
    const float r10 = a0 - bitsf(uH0), r11 = a1 - bitsf(uH1);
    const unsigned uM0 = fbits(r10) & 0xFFFF0000u, uM1 = fbits(r11) & 0xFFFF0000u;
    const float r20 = r10 - bitsf(uM0), r21 = r11 - bitsf(uM1);
    dH[v] = uH1 | (uH0 >> 16);
    dM[v] = uM1 | (uM0 >> 16);
    dL[v] = (fbits(r21) & 0xFFFF0000u) | (fbits(r20) >> 16);
  }
  H = mk8(dH[0],dH[1],dH[2],dH[3]);
  M = mk8(dM[0],dM[1],dM[2],dM[3]);
  L = mk8(dL[0],dL[1],dL[2],dL[3]);
}

__global__ __launch_bounds__(64) void init_out(float* __restrict__ out,
                                               const float* __restrict__ lso_p) {
  if (threadIdx.x == 0) *out = *lso_p;
}

// pre[t][m][k] = b1m[k] + x(t)@W1m[1:4,k] + tk*W1m[4,k]  — z-independent, fully parallel
__global__ __launch_bounds__(256) void pre_kernel(
    const float* __restrict__ X_seq,
    const float* __restrict__ dW1, const float* __restrict__ db1,
    const float* __restrict__ gW1, const float* __restrict__ gb1,
    const int* __restrict__ i0_p, float* __restrict__ pre)
{
  const int g = blockIdx.x * 256 + threadIdx.x;   // 512 blocks -> 131072 = 1024*2*64
  const int t = g >> 7;
  const int m = (g >> 6) & 1;
  const int k = g & 63;
  const float* W1 = m ? gW1 : dW1;
  const float* B1 = m ? gb1 : db1;
  const int i0 = *i0_p;
  const float tk = (float)(i0 + t);
  const float x0 = X_seq[(i0+t)*3 + 0];
  const float x1 = X_seq[(i0+t)*3 + 1];
  const float x2 = X_seq[(i0+t)*3 + 2];
  pre[g] = fmaf(tk, W1[4*64 + k],
           fmaf(x2, W1[3*64 + k],
           fmaf(x1, W1[2*64 + k],
           fmaf(x0, W1[1*64 + k], B1[k]))));
}

__global__ __launch_bounds__(256, 2) void sde_kernel(
    const float* __restrict__ X_seq, const float* __restrict__ y_seq,
    const float* __restrict__ kappa_p, const float* __restrict__ a_p,
    const float* __restrict__ b0_p, const float* __restrict__ b1_p,
    const float* __restrict__ b2_p, const float* __restrict__ S_p,
    const float* __restrict__ lso_p,
    const float* __restrict__ dW1,
    const float* __restrict__ dW2, const float* __restrict__ db2,
    const float* __restrict__ dW3, const float* __restrict__ db3,
    const float* __restrict__ gW1,
    const float* __restrict__ gW2, const float* __restrict__ gb2,
    const float* __restrict__ gW3, const float* __restrict__ gb3,
    const float* __restrict__ xi, const float* __restrict__ pre,
    const int* __restrict__ i0_p, const int* __restrict__ dt_p,
    float* __restrict__ out)
{
  // W2 split fragments, both MLPs, 3 levels: [m][lvl][c][jt][lane] = 48 KB.
  // Written once at init (single barrier), read-only in the loop.
  __shared__ bf16x8 Bf[2][3][2][4][64];

  const int tid    = threadIdx.x;
  const int l      = tid & 63;
  const int lane15 = l & 15;            // A-row(path) / B,C-col(j) index
  const int lg     = l >> 4;            // k-group / C-row group
  const int w      = __builtin_amdgcn_readfirstlane(tid >> 6); // wave 0..3
  const int gpath  = blockIdx.x * PPB + w * PPW + lane15;

  const float kappa = *kappa_p;
  const float a0 = a_p[0], a1 = a_p[1], a2 = a_p[2];
  const float b0 = *b0_p, b1c = *b1_p, b2c = *b2_p, S = *S_p, lso = *lso_p;
  const int   i0 = *i0_p;
  const float dtf  = (float)(*dt_p);
  const float sqdt = sqrtf(dtf);
  const float db3v = db3[0], gb3v = gb3[0];

  // ---- init: LDS B-fragments (each wave builds 4 of the 16 (m,c,jt) groups)
  #pragma unroll
  for (int gi = 0; gi < 4; ++gi) {
    const int gidx = w * 4 + gi;          // 0..15
    const int bm = gidx >> 3, bc = (gidx >> 2) & 1, bjt = gidx & 3;
    const float* W2 = bm ? gW2 : dW2;
    float e[8];
    #pragma unroll
    for (int q = 0; q < 8; ++q)
      e[q] = W2[(bc*32 + lg*8 + q)*64 + bjt*16 + lane15];
    bf16x8 H, M, L;
    split3(e, H, M, L);
    Bf[bm][0][bc][bjt][l] = H;
    Bf[bm][1][bc][bjt][l] = M;
    Bf[bm][2][bc][bjt][l] = L;
  }

  // ---- loop-invariant registers
  float w1z[2][2][8];                     // W1 row 0 (z coeff), both MLPs
  #pragma unroll
  for (int mm = 0; mm < 2; ++mm) {
    const float* W1 = mm ? gW1 : dW1;
    #pragma unroll
    for (int c = 0; c < 2; ++c)
      #pragma unroll
      for (int q = 0; q < 8; ++q)
        w1z[mm][c][q] = W1[c*32 + lg*8 + q];
  }
  float b2v[2][4], w3v[2][4];
  #pragma unroll
  for (int mm = 0; mm < 2; ++mm) {
    const float* B2 = mm ? gb2 : db2;
    const float* W3 = mm ? gW3 : dW3;
    #pragma unroll
    for (int jt = 0; jt < 4; ++jt) {
      b2v[mm][jt] = B2[jt*16 + lane15];
      w3v[mm][jt] = W3[jt*16 + lane15];
    }
  }

  __syncthreads();   // the ONLY barrier; Bf read-only hereafter

  // ---- state
  float y0 = y_seq[i0 - 1];
  y0 = fminf(fmaxf(y0, 1e-4f), 1.0f - 1e-4f);
  float z = logf(y0 / (1.0f - y0));
  float nacc = 0.0f;

  float x0 = X_seq[i0*3 + 0], x1 = X_seq[i0*3 + 1], x2 = X_seq[i0*3 + 2];
  float yk  = y_seq[i0];
  float xik = xi[gpath];

  #pragma unroll 1
  for (int t = 0; t < TSTEPS; ++t) {
    const float tk = (float)(i0 + t);

    // ---- pre loads for this step (z-independent; m=1's hide under m=0 compute)
    f32x4 pr[2][2][2];
    const float* pb = pre + (size_t)t * 128;
    #pragma unroll
    for (int mm = 0; mm < 2; ++mm)
      #pragma unroll
      for (int c = 0; c < 2; ++c) {
        const f32x4* pp = reinterpret_cast<const f32x4*>(pb + mm*64 + c*32 + lg*8);
        pr[mm][c][0] = pp[0];
        pr[mm][c][1] = pp[1];
      }

    // ---- prefetch next-step globals
    const int tn = (t + 1 < TSTEPS) ? t + 1 : t;
    const float xn0 = X_seq[(i0+tn)*3 + 0];
    const float xn1 = X_seq[(i0+tn)*3 + 1];
    const float xn2 = X_seq[(i0+tn)*3 + 2];
    const float yn  = y_seq[i0 + tn];
    const float xin = xi[(size_t)tn*NMC + gpath];

    float fg[2];
    #pragma unroll
    for (int mm = 0; mm < 2; ++mm) {
      // ---- layer 1 + A-fragments
      bf16x8 aH[2], aM[2], aL[2];
      #pragma unroll
      for (int c = 0; c < 2; ++c) {
        float e[8];
        #pragma unroll
        for (int q = 0; q < 4; ++q)
          e[q] = fsilu(fmaf(z, w1z[mm][c][q], pr[mm][c][0][q]));
        #pragma unroll
        for (int q = 0; q < 4; ++q)
          e[4+q] = fsilu(fmaf(z, w1z[mm][c][4+q], pr[mm][c][1][q]));
        split3(e, aH[c], aM[c], aL[c]);
      }

      // ---- layer 2: MFMA, B-frags streamed from LDS
      f32x4 acc[4];
      #pragma unroll
      for (int jt = 0; jt < 4; ++jt) {
        acc[jt][0] = b2v[mm][jt]; acc[jt][1] = b2v[mm][jt];
        acc[jt][2] = b2v[mm][jt]; acc[jt][3] = b2v[mm][jt];
      }
      #pragma unroll
      for (int c = 0; c < 2; ++c) {
        #pragma unroll
        for (int jt = 0; jt < 4; ++jt) {
          const bf16x8 bh = Bf[mm][0][c][jt][l];
          const bf16x8 bm_ = Bf[mm][1][c][jt][l];
          const bf16x8 bl = Bf[mm][2][c][jt][l];
          MFMA_B16(aH[c], bh,  acc[jt]);   // H*H
          MFMA_B16(aH[c], bm_, acc[jt]);   // H*M
          MFMA_B16(aM[c], bh,  acc[jt]);   // M*H
          MFMA_B16(aH[c], bl,  acc[jt]);   // H*L
          MFMA_B16(aL[c], bh,  acc[jt]);   // L*H
          MFMA_B16(aM[c], bm_, acc[jt]);   // M*M
        }
      }

      // ---- layer 3: s_r = sum_j silu(C[r][j])*W3[j]; C row = lg*4+r, col = jt*16+lane15
      float s0 = 0.0f, s1 = 0.0f, s2 = 0.0f, s3 = 0.0f;
      #pragma unroll
      for (int jt = 0; jt < 4; ++jt) {
        s0 = fmaf(fsilu(acc[jt][0]), w3v[mm][jt], s0);
        s1 = fmaf(fsilu(acc[jt][1]), w3v[mm][jt], s1);
        s2 = fmaf(fsilu(acc[jt][2]), w3v[mm][jt], s2);
        s3 = fmaf(fsilu(acc[jt][3]), w3v[mm][jt], s3);
      }
      // component-fold allreduce over the 16-lane group:
      // after 4 shfl steps, lane q holds s_{q&3} summed over its group.
      const float a01 = (lane15 & 1) ? s1 : s0;
      const float b01 = (lane15 & 1) ? s0 : s1;
      float u  = a01 + __shfl_xor(b01, 1, 64);
      const float a23 = (lane15 & 1) ? s3 : s2;
      const float b23 = (lane15 & 1) ? s2 : s3;
      float u2 = a23 + __shfl_xor(b23, 1, 64);
      const float aw = (lane15 & 2) ? u2 : u;
      const float bw = (lane15 & 2) ? u  : u2;
      float wv = aw + __shfl_xor(bw, 2, 64);
      wv += __shfl_xor(wv, 4, 64);
      wv += __shfl_xor(wv, 8, 64);
      // lane needs value for path=lane15: it lives in group lane15>>2, component lane15&3
      fg[mm] = __shfl(wv, (lane15 >> 2) * 16 + (lane15 & 3), 64);
    }

    // ---- combine (all wave-local now; no barrier)
    const float f  = fg[0] + db3v;
    const float gp = fg[1] + gb3v;
    const float ax = fabsf(gp);
    const float g  = fmaxf(gp, 0.0f) + __logf(1.0f + __expf(-ax)) + 1e-6f;

    const float ang = TWO_PI * tk / S;
    const float mu  = fmaf(x0, a0, fmaf(x1, a1, x2 * a2)) + b0
                      + b1c * __sinf(ang) + b2c * __cosf(ang);
    z = z + (kappa * (mu - z) + f) * dtf + g * sqdt * xik;

    if (lg == 0) {
      const float U = __fdividef(1.0f, 1.0f + __expf(-z));
      const float d = yk - U;
      nacc = fmaf(d, d, nacc);
    }

    x0 = xn0; x1 = xn1; x2 = xn2; yk = yn; xik = xin;
  }

  // ---- reduction: nacc nonzero only in lanes 0..15 of each wave
  float v = nacc;
  #pragma unroll
  for (int off = 1; off < 64; off <<= 1) v += __shfl_xor(v, off, 64);
  if (l == 0) {
    const float sobs  = __expf(lso) + 1e-8f;
    const float scale = 0.5f / (sobs * sobs) / ((float)TSTEPS * (float)NMC);
    atomicAdd(out, v * scale);
  }
}

extern "C" void kernel_launch(void* const* d_in, const int* in_sizes, int n_in,
                              void* d_out, int out_size, void* d_ws, size_t ws_size,
                              hipStream_t stream) {
  const float* X_seq = (const float*)d_in[0];
  const float* y_seq = (const float*)d_in[1];
  const float* kappa = (const float*)d_in[2];
  const float* a     = (const float*)d_in[3];
  const float* b0    = (const float*)d_in[4];
  const float* b1    = (const float*)d_in[5];
  const float* b2    = (const float*)d_in[6];
  const float* S     = (const float*)d_in[7];
  const float* lso   = (const float*)d_in[8];
  const float* dW1   = (const float*)d_in[9];
  const float* db1   = (const float*)d_in[10];
  const float* dW2   = (const float*)d_in[11];
  const float* db2   = (const float*)d_in[12];
  const float* dW3   = (const float*)d_in[13];
  const float* db3   = (const float*)d_in[14];
  const float* gW1   = (const float*)d_in[15];
  const float* gb1   = (const float*)d_in[16];
  const float* gW2   = (const float*)d_in[17];
  const float* gb2   = (const float*)d_in[18];
  const float* gW3   = (const float*)d_in[19];
  const float* gb3   = (const float*)d_in[20];
  const float* xi    = (const float*)d_in[21];
  const int*   i0    = (const int*)d_in[22];
  const int*   dt    = (const int*)d_in[23];
  float* out = (float*)d_out;
  float* pre = (float*)d_ws;   // TSTEPS*2*64 floats = 512 KB

  hipLaunchKernelGGL(init_out, dim3(1), dim3(64), 0, stream, out, lso);
  hipLaunchKernelGGL(pre_kernel, dim3(512), dim3(256), 0, stream,
                     X_seq, dW1, db1, gW1, gb1, i0, pre);
  hipLaunchKernelGGL(sde_kernel, dim3(NBLK), dim3(256), 0, stream,
                     X_seq, y_seq, kappa, a, b0, b1, b2, S, lso,
                     dW1, dW2, db2, dW3, db3,
                     gW1, gW2, gb2, gW3, gb3,
                     xi, pre, i0, dt, out);
}